// Round 10
// baseline (412.150 us; speedup 1.0000x reference)
//
#include <hip/hip_runtime.h>
#include <hip/hip_bf16.h>
#include <math.h>

// N = 65536 nodes, E = 524288 edges, HID = 128, 128 graphs x 512 nodes
// fp32 throughout: absmax threshold ~9.8e-8 forbids bf16 MFMA (and 3-way
// bf16-split MFMA needs 6 terms -> no win at this skinny shape).
// Embedding GEMM folded into layer-0 weights: x@(embW@W0)+embb@W0.
// PADDED CSR (48 slots/node) built INSIDE gemm0's dispatch (blocks >= gb).
// All D^-1/2 scaling applied in aggregate (per-src rsqrt(cnt+1), cnt L2-hot)
// so gemm never reads cnt -> no race with the in-dispatch build.

#define SLOTS 48
#define FLAT  12   // flat gather batch; P(deg>12 | Poisson(8)) ~ 6.6% -> tail

static __device__ __forceinline__ float4 f4add(float4 a, float4 b) {
    return make_float4(a.x + b.x, a.y + b.y, a.z + b.z, a.w + b.w);
}
static __device__ __forceinline__ float4 f4fma(float s, float4 a, float4 acc) {
    return make_float4(fmaf(s, a.x, acc.x), fmaf(s, a.y, acc.y),
                       fmaf(s, a.z, acc.z), fmaf(s, a.w, acc.w));
}

// ================== Weight fold: [embW; embb](129x128) @ W0 ================
__global__ __launch_bounds__(256) void fold_emb(
    const float* __restrict__ embW, const float* __restrict__ embb,
    const float* __restrict__ W0, float* __restrict__ W01,
    float* __restrict__ b01)
{
    __shared__ float rs[128];
    __shared__ float part[256];
    const int r = blockIdx.x;   // 0..128; r==128 -> bias row
    const int t = threadIdx.x;
    const int c = t & 127, q = t >> 7;  // q in {0,1}
    if (t < 128) rs[t] = (r < 128) ? embW[r * 128 + t] : embb[t];
    __syncthreads();
    float s = 0.f;
    const int k0 = q * 64;
#pragma unroll 8
    for (int k = k0; k < k0 + 64; k++) s = fmaf(rs[k], W0[k * 128 + c], s);
    part[t] = s;
    __syncthreads();
    if (q == 0) {
        float v = part[c] + part[c + 128];
        if (r < 128) W01[r * 128 + c] = v;
        else         b01[c] = v;
    }
}

// ====================== GEMM (+ optional CSR build blocks) ==================
// Proven round-5/8 structure (44.4us plateau): BM=128, 256 thr, 8x8 microtile,
// single-buffered LDS (50.8KB -> 3 blocks/CU), register prefetch.
// ASTRIDE=257: A-stores uniform 2-way bank aliasing (free, m136); A-reads
// 16-lane broadcasts. WSTRIDE=140 + col swizzle c->c+4*(c>>5) (injective,
// max 139 -- 132 was the round-4 correctness bug).
// Blocks >= gb run the edge count+scatter (layer-0 launch only); gemm blocks
// never read cnt (dinv applied in aggregate) -> no race.
// Epilogue: out = acc + bias  (bias nullable)
#define ASTRIDE 257
#define WSTRIDE 140
__global__ __launch_bounds__(256) void gemm128(
    const float* __restrict__ A, const float* __restrict__ W,
    const float* __restrict__ bias, float* __restrict__ out,
    const int* __restrict__ src, const int* __restrict__ dst,
    int* __restrict__ cnt, int* __restrict__ csr_pad, int E, int gb)
{
    const int bid = blockIdx.x;
    if (bid >= gb) {   // ---- CSR build blocks (layer-0 dispatch only) ----
        int e = (bid - gb) * 256 + threadIdx.x;
        if (e < E) {
            int d = dst[e];
            int r = atomicAdd(&cnt[d], 1);
            if (r < SLOTS) csr_pad[d * SLOTS + r] = src[e];
        }
        return;
    }

    __shared__ float As[32 * ASTRIDE];  // [k][m] transposed
    __shared__ float Ws[32 * WSTRIDE];  // [k][c'] swizzled
    const int tid  = threadIdx.x;
    const int rb   = bid * 128;
    const int tc   = tid & 15;
    const int tr   = tid >> 4;
    const int colg = tc * 8;
    const int cswz = colg + ((colg >> 5) << 2);
    const int rowg = tr * 8;

    const int a_kq = tid & 7;
    const int a_m  = tid >> 3;
    const int w_c  = (tid & 31) * 4;
    const int w_cs = w_c + ((w_c >> 5) << 2);
    const int w_k  = tid >> 5;

    float acc[8][8];
#pragma unroll
    for (int i = 0; i < 8; i++)
#pragma unroll
        for (int j = 0; j < 8; j++) acc[i][j] = 0.f;

    float4 areg[4], wreg[4];
#pragma unroll
    for (int t = 0; t < 4; t++)
        areg[t] = *(const float4*)&A[(size_t)(rb + t * 32 + a_m) * 128 + a_kq * 4];
#pragma unroll
    for (int t = 0; t < 4; t++)
        wreg[t] = *(const float4*)&W[(size_t)(t * 8 + w_k) * 128 + w_c];

#pragma unroll 1
    for (int k0 = 0; k0 < 128; k0 += 32) {
#pragma unroll
        for (int t = 0; t < 4; t++) {
            const int m = t * 32 + a_m;
            const float4 av = areg[t];
            As[(a_kq * 4 + 0) * ASTRIDE + m] = av.x;
            As[(a_kq * 4 + 1) * ASTRIDE + m] = av.y;
            As[(a_kq * 4 + 2) * ASTRIDE + m] = av.z;
            As[(a_kq * 4 + 3) * ASTRIDE + m] = av.w;
        }
#pragma unroll
        for (int t = 0; t < 4; t++)
            *(float4*)&Ws[(t * 8 + w_k) * WSTRIDE + w_cs] = wreg[t];
        __syncthreads();
        if (k0 < 96) {
#pragma unroll
            for (int t = 0; t < 4; t++)
                areg[t] = *(const float4*)&A[(size_t)(rb + t * 32 + a_m) * 128 + k0 + 32 + a_kq * 4];
#pragma unroll
            for (int t = 0; t < 4; t++)
                wreg[t] = *(const float4*)&W[(size_t)(k0 + 32 + t * 8 + w_k) * 128 + w_c];
        }
#pragma unroll 8
        for (int kk = 0; kk < 32; kk++) {
            float4 a0 = *(const float4*)&As[kk * ASTRIDE + rowg];
            float4 a1 = *(const float4*)&As[kk * ASTRIDE + rowg + 4];
            float4 b0 = *(const float4*)&Ws[kk * WSTRIDE + cswz];
            float4 b1 = *(const float4*)&Ws[kk * WSTRIDE + cswz + 4];
            float av[8] = {a0.x, a0.y, a0.z, a0.w, a1.x, a1.y, a1.z, a1.w};
            float bv[8] = {b0.x, b0.y, b0.z, b0.w, b1.x, b1.y, b1.z, b1.w};
#pragma unroll
            for (int i = 0; i < 8; i++)
#pragma unroll
                for (int j = 0; j < 8; j++) acc[i][j] = fmaf(av[i], bv[j], acc[i][j]);
        }
        __syncthreads();
    }

    float4 bb0 = make_float4(0.f, 0.f, 0.f, 0.f), bb1 = bb0;
    if (bias) {
        bb0 = *(const float4*)&bias[colg];
        bb1 = *(const float4*)&bias[colg + 4];
    }
#pragma unroll
    for (int i = 0; i < 8; i++) {
        const int row = rb + rowg + i;
        float4 o0, o1;
        o0.x = acc[i][0] + bb0.x;  o0.y = acc[i][1] + bb0.y;
        o0.z = acc[i][2] + bb0.z;  o0.w = acc[i][3] + bb0.w;
        o1.x = acc[i][4] + bb1.x;  o1.y = acc[i][5] + bb1.y;
        o1.z = acc[i][6] + bb1.z;  o1.w = acc[i][7] + bb1.w;
        *(float4*)&out[(size_t)row * 128 + colg]     = o0;
        *(float4*)&out[(size_t)row * 128 + colg + 4] = o1;
    }
}

// ============================ Aggregation ===================================
// h_out[i] = relu( dinv_i*( dinv_i*hs[i] + sum_j dinv_j*hs[src_j] ) + b )
// with dinv = rsqrt(deg+1), applied entirely here (gemm never reads cnt).
// 32 lanes/node (float4 per lane), 8 nodes per 256-thread block; FLAT=12
// rows gathered unconditionally (masked), tail loop for deg>12 (~6.6%).
__global__ __launch_bounds__(256) void aggregate(
    const float* __restrict__ hs, const int* __restrict__ csr_pad,
    const int* __restrict__ cnt, const float* __restrict__ bias,
    float* __restrict__ hout,
    const float* __restrict__ pool_p, float* __restrict__ scores, int n)
{
    const int grp  = threadIdx.x >> 5;
    const int lane = threadIdx.x & 31;
    const int node = blockIdx.x * 8 + grp;
    const float4* __restrict__ hv = (const float4*)hs;

    const int deg = cnt[node];
    const int e0  = node * SLOTS;

    int   ix[FLAT];
    float dj[FLAT];
#pragma unroll
    for (int j = 0; j < FLAT; j++) {
        const int raw = csr_pad[e0 + j];   // always in-bounds memory
        ix[j] = (j < deg) ? raw : node;    // clamp poison before use
    }
#pragma unroll
    for (int j = 0; j < FLAT; j++)
        dj[j] = (j < deg) ? rsqrtf((float)(cnt[ix[j]] + 1)) : 0.f;

    const float dv = rsqrtf((float)(deg + 1));
    float4 self = hv[(size_t)node * 32 + lane];
    float4 r[FLAT];
#pragma unroll
    for (int j = 0; j < FLAT; j++)
        r[j] = hv[(size_t)ix[j] * 32 + lane];
    asm volatile("" ::: "memory");  // keep the gathers in flight before use

    float4 a0 = make_float4(self.x * dv, self.y * dv, self.z * dv, self.w * dv);
    float4 a1 = make_float4(0.f, 0.f, 0.f, 0.f);
    float4 a2 = a1, a3 = a1;
#pragma unroll
    for (int j = 0; j < FLAT; j += 4) {
        a0 = f4fma(dj[j + 0], r[j + 0], a0);
        a1 = f4fma(dj[j + 1], r[j + 1], a1);
        a2 = f4fma(dj[j + 2], r[j + 2], a2);
        a3 = f4fma(dj[j + 3], r[j + 3], a3);
    }
    const int dcap = deg < SLOTS ? deg : SLOTS;
    for (int j = FLAT; j < dcap; j++) {  // tail (deg > 12)
        const int idx = csr_pad[e0 + j];
        a1 = f4fma(rsqrtf((float)(cnt[idx] + 1)), hv[(size_t)idx * 32 + lane], a1);
    }

    float4 s = f4add(f4add(a0, a1), f4add(a2, a3));
    const float4 bb = ((const float4*)bias)[lane];
    float4 o;
    o.x = fmaxf(fmaf(s.x, dv, bb.x), 0.f);
    o.y = fmaxf(fmaf(s.y, dv, bb.y), 0.f);
    o.z = fmaxf(fmaf(s.z, dv, bb.z), 0.f);
    o.w = fmaxf(fmaf(s.w, dv, bb.w), 0.f);
    ((float4*)hout)[(size_t)node * 32 + lane] = o;

    if (scores) {  // wave-uniform branch (fused pooling score)
        float4 pv = ((const float4*)pool_p)[lane];
        float d  = o.x * pv.x + o.y * pv.y + o.z * pv.z + o.w * pv.w;
        float nn = pv.x * pv.x + pv.y * pv.y + pv.z * pv.z + pv.w * pv.w;
#pragma unroll
        for (int off = 16; off > 0; off >>= 1) {
            d  += __shfl_xor(d, off);
            nn += __shfl_xor(nn, off);
        }
        if (lane == 0) scores[node] = d * rsqrtf(nn);
    }
}

// ==================== TopK pool (k=256 of 512) + MLP head ===================
// 1024 threads/block: doubles waves/CU for the 16MB gather (128 blocks only).
__global__ __launch_bounds__(1024) void topk_mlp(
    const float* __restrict__ scores, const float* __restrict__ h,
    const float* __restrict__ fc1W, const float* __restrict__ fc1b,
    const float* __restrict__ fc2W, const float* __restrict__ fc2b,
    const float* __restrict__ fc3W, const float* __restrict__ fc3b,
    float* __restrict__ out)
{
    __shared__ float s[512];
    __shared__ int   sel[256];
    __shared__ float w[256];
    __shared__ float4 red[1024];
    __shared__ float pld[128];
    __shared__ float z1[128];
    __shared__ float z2[64];
    const int g = blockIdx.x;
    const int i = threadIdx.x;
    if (i < 512) s[i] = scores[g * 512 + i];
    __syncthreads();
    if (i < 512) {
        float si = s[i];
        int rank = 0;
        for (int j = 0; j < 512; j++) {
            float sj = s[j];
            rank += (sj > si) || (sj == si && j < i);
        }
        if (rank < 256) {
            sel[rank] = i;
            w[rank]   = tanhf(si) * (1.f / 256.f);
        }
    }
    __syncthreads();
    const int c   = (i & 31) * 4;
    const int grp = i >> 5;           // 32 groups of 8 rows each
    float4 acc = make_float4(0.f, 0.f, 0.f, 0.f);
    for (int t = grp; t < 256; t += 32) {
        float wt  = w[t];
        int   idx = sel[t];
        float4 r = *(const float4*)&h[((size_t)g * 512 + idx) * 128 + c];
        acc = f4fma(wt, r, acc);
    }
    red[i] = acc;
    __syncthreads();
    if (i < 512) red[i] = f4add(red[i], red[i + 512]);
    __syncthreads();
    if (i < 256) red[i] = f4add(red[i], red[i + 256]);
    __syncthreads();
    if (i < 128) red[i] = f4add(red[i], red[i + 128]);
    __syncthreads();
    if (i < 64) red[i] = f4add(red[i], red[i + 64]);
    __syncthreads();
    if (i < 32) {
        float4 v = f4add(red[i], red[i + 32]);
        *(float4*)&pld[i * 4] = v;
    }
    __syncthreads();
    if (i < 128) {
        float a = fc1b[i];
        for (int k = 0; k < 128; k++) a += pld[k] * fc1W[k * 128 + i];
        z1[i] = fmaxf(a, 0.f);
    }
    __syncthreads();
    if (i < 64) {
        float b = fc2b[i];
        for (int k = 0; k < 128; k++) b += z1[k] * fc2W[k * 64 + i];
        z2[i] = fmaxf(b, 0.f);
    }
    __syncthreads();
    if (i < 10) {
        float o = fc3b[i];
        for (int k = 0; k < 64; k++) o += z2[k] * fc3W[k * 10 + i];
        out[g * 10 + i] = o;
    }
}

// ============================ Launcher ======================================
extern "C" void kernel_launch(void* const* d_in, const int* in_sizes, int n_in,
                              void* d_out, int out_size, void* d_ws, size_t ws_size,
                              hipStream_t stream)
{
    const float* x     = (const float*)d_in[0];
    const int*   eidx  = (const int*)d_in[1];
    const float* embW  = (const float*)d_in[3];
    const float* embb  = (const float*)d_in[4];
    const float* gcnW  = (const float*)d_in[5];
    const float* gcnb  = (const float*)d_in[6];
    const float* poolp = (const float*)d_in[7];
    const float* fc1W  = (const float*)d_in[8];
    const float* fc1b  = (const float*)d_in[9];
    const float* fc2W  = (const float*)d_in[10];
    const float* fc2b  = (const float*)d_in[11];
    const float* fc3W  = (const float*)d_in[12];
    const float* fc3b  = (const float*)d_in[13];
    float* out = (float*)d_out;

    const int n = in_sizes[0] / 128;   // 65536
    const int E = in_sizes[1] / 2;     // 524288
    const int G = n / 512;             // 128

    const int* src = eidx;
    const int* dst = eidx + E;

    char* ws = (char*)d_ws;
    size_t off = 0;
    auto carve = [&](size_t bytes) {
        void* p = ws + off;
        off += (bytes + 255) & ~(size_t)255;
        return p;
    };
    float* h       = (float*)carve((size_t)n * 128 * 4);
    float* hs      = (float*)carve((size_t)n * 128 * 4);
    int*   cnt     = (int*)carve((size_t)n * 4);
    int*   csr_pad = (int*)carve((size_t)n * SLOTS * 4);
    float* scores  = (float*)carve((size_t)n * 4);
    float* W01     = (float*)carve(128 * 128 * 4);
    float* b01     = (float*)carve(128 * 4);
    (void)ws_size;

    const int gb = n / 128;            // 512 gemm blocks
    const int EB = E / 256;            // 2048 edge blocks

    // 1. zero degree counters
    hipMemsetAsync(cnt, 0, (size_t)n * 4, stream);
    // 2. weight fold (must complete before gemm0 reads W01)
    fold_emb<<<129, 256, 0, stream>>>(embW, embb, gcnW, W01, b01);
    // 3. layer-0 gemm + CSR build in ONE dispatch (disjoint block ranges)
    gemm128<<<gb + EB, 256, 0, stream>>>(x, W01, b01, hs,
                                         src, dst, cnt, csr_pad, E, gb);
    // 4. layer-0 aggregate
    aggregate<<<n / 8, 256, 0, stream>>>(hs, csr_pad, cnt, gcnb, h,
                                         poolp, nullptr, n);
    // 5-8. layers 1,2 (score fused into last aggregate)
    for (int l = 1; l < 3; l++) {
        gemm128<<<gb, 256, 0, stream>>>(h, gcnW + (size_t)l * 128 * 128,
                                        nullptr, hs,
                                        nullptr, nullptr, nullptr, nullptr, 0, gb);
        aggregate<<<n / 8, 256, 0, stream>>>(
            hs, csr_pad, cnt, gcnb + (size_t)l * 128, h,
            poolp, (l == 2) ? scores : nullptr, n);
    }
    // 9. fused topk pool + MLP
    topk_mlp<<<G, 1024, 0, stream>>>(scores, h, fc1W, fc1b, fc2W, fc2b,
                                     fc3W, fc3b, out);
}